// Round 1
// baseline (7370.750 us; speedup 1.0000x reference)
//
#include <hip/hip_runtime.h>
#include <cstddef>

// ---------------------------------------------------------------------------
// SegTransformerDecoder — fp32 correctness-first implementation.
// Layout notes:
//   q / conv activations: channel-major [c][pix], pix = y*100 + x, HW=10000
//   ref points:  [pix][p][3]   (24 floats per pixel)
//   sw weights:  [pix][p][l]   (32 floats per pixel, softmaxed over l)
//   featT:       [n][y][x][c]  (channel-last, 132 ch) per level
//   sf:          channel-major [256][pix]  (0..127 feats fold, 128..255 weighted fold)
// ---------------------------------------------------------------------------

#define HW   10000
#define WID  100

__device__ __forceinline__ float gelu_exact(float x) {
    return 0.5f * x * (1.0f + erff(x * 0.7071067811865475f));
}

// Direct conv KSxKS (pad = KS/2), weights for one output channel staged in LDS.
// grid = (ceil(HW/256), Cout), block = 256. Optional exact-GELU and residual add.
template<int CIN, int KS, bool ACT, bool RES>
__global__ void conv_k(const float* __restrict__ in, const float* __restrict__ w,
                       const float* __restrict__ bias, const float* __restrict__ res,
                       float* __restrict__ out)
{
    constexpr int PAD = KS / 2;
    const int oc  = blockIdx.y;
    const int pix = blockIdx.x * blockDim.x + threadIdx.x;
    extern __shared__ float wsm[];                 // CIN*KS*KS floats
    const int WN = CIN * KS * KS;
    for (int i = threadIdx.x; i < WN; i += blockDim.x) wsm[i] = w[oc * WN + i];
    __syncthreads();
    if (pix >= HW) return;
    const int y = pix / WID, x = pix % WID;
    float acc = bias[oc];
    for (int ic = 0; ic < CIN; ++ic) {
        const float* ip = in + ic * HW;
        const float* wp = wsm + ic * KS * KS;
#pragma unroll
        for (int ky = 0; ky < KS; ++ky) {
            const int iy = y + ky - PAD;
            if (iy < 0 || iy >= WID) continue;
#pragma unroll
            for (int kx = 0; kx < KS; ++kx) {
                const int ix = x + kx - PAD;
                if (ix < 0 || ix >= WID) continue;
                acc = fmaf(ip[iy * WID + ix], wp[ky * KS + kx], acc);
            }
        }
    }
    if (ACT) acc = gelu_exact(acc);
    if (RES) acc += res[oc * HW + pix];
    out[oc * HW + pix] = acc;
}

// 1x1 conv, grid = (ceil(HW/256), Cout)
template<int CIN, bool ACT>
__global__ void conv1x1_k(const float* __restrict__ in, const float* __restrict__ w,
                          const float* __restrict__ bias, float* __restrict__ out)
{
    const int oc  = blockIdx.y;
    const int pix = blockIdx.x * blockDim.x + threadIdx.x;
    extern __shared__ float wsm[];                 // CIN floats
    for (int i = threadIdx.x; i < CIN; i += blockDim.x) wsm[i] = w[oc * CIN + i];
    __syncthreads();
    if (pix >= HW) return;
    float acc = bias[oc];
    for (int ic = 0; ic < CIN; ++ic)
        acc = fmaf(in[ic * HW + pix], wsm[ic], acc);
    if (ACT) acc = gelu_exact(acc);
    out[oc * HW + pix] = acc;
}

// Instance norm over spatial dims; one block (256 thr) per channel.
__global__ void inorm_k(const float* __restrict__ in, float* __restrict__ out)
{
    const int c = blockIdx.x;
    const float* p = in + c * HW;
    __shared__ float red[256];
    const int tid = threadIdx.x;

    float s = 0.f;
    for (int i = tid; i < HW; i += 256) s += p[i];
    red[tid] = s; __syncthreads();
    for (int o = 128; o > 0; o >>= 1) { if (tid < o) red[tid] += red[tid + o]; __syncthreads(); }
    const float mean = red[0] * 1e-4f;
    __syncthreads();

    float v = 0.f;
    for (int i = tid; i < HW; i += 256) { const float d = p[i] - mean; v += d * d; }
    red[tid] = v; __syncthreads();
    for (int o = 128; o > 0; o >>= 1) { if (tid < o) red[tid] += red[tid + o]; __syncthreads(); }
    const float rstd = rsqrtf(red[0] * 1e-4f + 1e-5f);

    float* op = out + c * HW;
    for (int i = tid; i < HW; i += 256) op[i] = (p[i] - mean) * rstd;
}

// Fused: 1x1 off conv (24ch) + sigmoid + affine + bev_pos transform -> ref[pix][p][3]
//        1x1 sw conv (32ch) + softmax over L -> swts[pix][p][l]
// grid = HW blocks of 64 threads.
__global__ void offsw_k(const float* __restrict__ qn, const float* __restrict__ bev_pos,
                        const float* __restrict__ off_w, const float* __restrict__ off_b,
                        const float* __restrict__ sw_w, const float* __restrict__ sw_b,
                        float* __restrict__ refp, float* __restrict__ swts)
{
    const int pix = blockIdx.x;
    const int tid = threadIdx.x;                   // 64
    __shared__ float qv[128];
    __shared__ float swraw[32];
    qv[tid]      = qn[tid * HW + pix];
    qv[tid + 64] = qn[(tid + 64) * HW + pix];
    __syncthreads();

    if (tid < 24) {
        float acc = off_b[tid];
        for (int c = 0; c < 128; ++c) acc = fmaf(qv[c], off_w[tid * 128 + c], acc);
        const float s = 1.0f / (1.0f + expf(-acc));
        const int coord = tid % 3;
        const float rng = (coord < 2) ? 0.250001f : 4.000001f;   // 0.25*scale+EPS / 4.0+EPS
        const float v = s * rng * 2.0f - rng;
        const float lo[3]   = {-50.f, -50.f, -5.f};
        const float span[3] = {100.f, 100.f, 8.f};
        refp[pix * 24 + tid] = bev_pos[pix * 3 + coord] * span[coord] + lo[coord] + v;
    } else if (tid >= 32) {
        const int j = tid - 32;
        float acc = sw_b[j];
        for (int c = 0; c < 128; ++c) acc = fmaf(qv[c], sw_w[j * 128 + c], acc);
        swraw[j] = acc;
    }
    __syncthreads();
    if (tid < 8) {
        float m = -1e30f;
#pragma unroll
        for (int l = 0; l < 4; ++l) m = fmaxf(m, swraw[tid * 4 + l]);
        float e[4], sum = 0.f;
#pragma unroll
        for (int l = 0; l < 4; ++l) { e[l] = expf(swraw[tid * 4 + l] - m); sum += e[l]; }
        const float inv = 1.0f / sum;
#pragma unroll
        for (int l = 0; l < 4; ++l) swts[pix * 32 + tid * 4 + l] = e[l] * inv;
    }
}

// Transpose one level: in [n][c][y][x] (c=132) -> out [n][y][x][c]
__global__ void transpose_feat_k(const float* __restrict__ in, float* __restrict__ out,
                                 int Hl, int Wl)
{
    const int total = 6 * 132 * Hl * Wl;
    for (int i = blockIdx.x * blockDim.x + threadIdx.x; i < total; i += gridDim.x * blockDim.x) {
        int c = i % 132;
        int t = i / 132;
        const int x = t % Wl; t /= Wl;
        const int y = t % Hl; t /= Hl;
        const int n = t;
        out[i] = in[((n * 132 + c) * Hl + y) * Wl + x];
    }
}

// Per-pixel: project 8 points into 6 cams, bilinear-sample 4 levels (132 ch),
// weight by softmax sw, sum over cams+levels, then distance-reweighted fold
// over p.  Writes sf[256][pix].  grid = HW blocks of 128 threads (thread = ch).
__global__ void sample_k(const float* __restrict__ refp, const float* __restrict__ swts,
                         const float* __restrict__ l2i,
                         const float* __restrict__ fT0, const float* __restrict__ fT1,
                         const float* __restrict__ fT2, const float* __restrict__ fT3,
                         float* __restrict__ sf)
{
    const int pix = blockIdx.x;
    const int tid = threadIdx.x;                   // 128
    __shared__ float rp[24], sw[32], M[96], tailv[32];
    if (tid < 24) rp[tid] = refp[pix * 24 + tid];
    if (tid < 32) sw[tid] = swts[pix * 32 + tid];
    if (tid < 96) M[tid]  = l2i[tid];
    __syncthreads();

    const float* fT[4] = {fT0, fT1, fT2, fT3};
    const int HL[4] = {32, 16, 8, 4};
    const int WL[4] = {88, 44, 22, 11};

    float sf1 = 0.f, sf2 = 0.f;
    for (int p = 0; p < 8; ++p) {
        float acc = 0.f, accT = 0.f;
        const float X = rp[p * 3], Y = rp[p * 3 + 1], Z = rp[p * 3 + 2];
        for (int n = 0; n < 6; ++n) {
            const float* m = M + n * 16;
            const float cx = m[0] * X + m[1] * Y + m[2]  * Z + m[3];
            const float cy = m[4] * X + m[5] * Y + m[6]  * Z + m[7];
            const float cz = m[8] * X + m[9] * Y + m[10] * Z + m[11];
            const bool valid = cz > 1e-5f;
            const float zz = fmaxf(cz, 1e-5f);
            const float gx = valid ? (cx / zz) * (2.0f / 704.0f) - 1.0f : -2.0f;
            const float gy = valid ? (cy / zz) * (2.0f / 256.0f) - 1.0f : -2.0f;
#pragma unroll
            for (int l = 0; l < 4; ++l) {
                const float wl = sw[p * 4 + l];
                const int Hl = HL[l], Wl = WL[l];
                const float fx = (gx + 1.0f) * 0.5f * (float)Wl - 0.5f;
                const float fy = (gy + 1.0f) * 0.5f * (float)Hl - 0.5f;
                // any-tap-in-bounds requires floor(fx) in [-1, Wl-1]:
                if (!(fx >= -1.0f && fx < (float)Wl && fy >= -1.0f && fy < (float)Hl))
                    continue;
                const float x0f = floorf(fx), y0f = floorf(fy);
                const int x0 = (int)x0f, y0 = (int)y0f;
                const int x1 = x0 + 1, y1 = y0 + 1;
                const float wx1 = fx - x0f, wy1 = fy - y0f;
                const float wx0 = 1.0f - wx1, wy0 = 1.0f - wy1;
                const bool okx0 = (x0 >= 0), okx1 = (x1 < Wl);
                const bool oky0 = (y0 >= 0), oky1 = (y1 < Hl);
                const float* fb = fT[l] + (size_t)n * Hl * Wl * 132;
                if (okx0 && oky0) {
                    const float wt = wx0 * wy0 * wl;
                    const float* t = fb + (size_t)(y0 * Wl + x0) * 132;
                    acc = fmaf(t[tid], wt, acc);
                    if (tid < 4) accT = fmaf(t[128 + tid], wt, accT);
                }
                if (okx1 && oky0) {
                    const float wt = wx1 * wy0 * wl;
                    const float* t = fb + (size_t)(y0 * Wl + x1) * 132;
                    acc = fmaf(t[tid], wt, acc);
                    if (tid < 4) accT = fmaf(t[128 + tid], wt, accT);
                }
                if (okx0 && oky1) {
                    const float wt = wx0 * wy1 * wl;
                    const float* t = fb + (size_t)(y1 * Wl + x0) * 132;
                    acc = fmaf(t[tid], wt, acc);
                    if (tid < 4) accT = fmaf(t[128 + tid], wt, accT);
                }
                if (okx1 && oky1) {
                    const float wt = wx1 * wy1 * wl;
                    const float* t = fb + (size_t)(y1 * Wl + x1) * 132;
                    acc = fmaf(t[tid], wt, acc);
                    if (tid < 4) accT = fmaf(t[128 + tid], wt, accT);
                }
            }
        }
        if (tid < 4) tailv[p * 4 + tid] = accT;
        __syncthreads();
        const float dx = X - tailv[p * 4 + 0];
        const float dy = Y - tailv[p * 4 + 1];
        const float dz = Z - tailv[p * 4 + 2];
        const float wgt = expf(-0.1f * (dx * dx + dy * dy + dz * dz));
        sf1 += acc;
        sf2 += acc * wgt;
    }
    sf[tid * HW + pix]         = sf1;
    sf[(128 + tid) * HW + pix] = sf2;
}

// ---------------------------------------------------------------------------

extern "C" void kernel_launch(void* const* d_in, const int* in_sizes, int n_in,
                              void* d_out, int out_size, void* d_ws, size_t ws_size,
                              hipStream_t stream)
{
    const float* bev_query = (const float*)d_in[0];
    const float* bev_pos   = (const float*)d_in[1];
    const float* l2i       = (const float*)d_in[2];
    const float* feat0     = (const float*)d_in[3];
    const float* feat1     = (const float*)d_in[4];
    const float* feat2     = (const float*)d_in[5];
    const float* feat3     = (const float*)d_in[6];
    const float* in_w      = (const float*)d_in[7];
    const float* in_b      = (const float*)d_in[8];
    const float* off_w     = (const float*)d_in[9];
    const float* off_b     = (const float*)d_in[10];
    const float* sw_w      = (const float*)d_in[11];
    const float* sw_b      = (const float*)d_in[12];
    const float* mid_w1    = (const float*)d_in[13];
    const float* mid_b1    = (const float*)d_in[14];
    const float* mid_w2    = (const float*)d_in[15];
    const float* mid_b2    = (const float*)d_in[16];
    const float* mid_w3    = (const float*)d_in[17];
    const float* mid_b3    = (const float*)d_in[18];
    const float* out_w     = (const float*)d_in[19];
    const float* out_b     = (const float*)d_in[20];
    float* out = (float*)d_out;

    float* ws = (float*)d_ws;
    // workspace layout (floats)
    float* qn   = ws;                      // 1,280,000   normalized q (reused for q2n)
    float* refp = qn   + 1280000;          //   240,000
    float* swts = refp + 240000;           //   320,000
    float* fT   = swts + 320000;           // 2,962,080   transposed feats
    float* sf   = fT   + 2962080;          // 2,560,000
    float* m1   = sf   + 2560000;          // 5,120,000
    float* m2   = m1   + 5120000;          // 5,120,000
    float* tmp  = m2   + 5120000;          // 1,280,000   pre-norm q1/q2/q3
    float* fT0 = fT;
    float* fT1 = fT0 + 6 * 132 * 32 * 88;  // +2,230,272
    float* fT2 = fT1 + 6 * 132 * 16 * 44;  // +  557,568
    float* fT3 = fT2 + 6 * 132 * 8  * 22;  // +  139,392

    const dim3 blk(256);
    const int PX = (HW + 255) / 256;       // 40

    // 1. q1 = bev_query + conv5x5(bev_query)
    hipLaunchKernelGGL((conv_k<128, 5, false, true>), dim3(PX, 128), blk,
                       128 * 25 * sizeof(float), stream,
                       bev_query, in_w, in_b, bev_query, tmp);
    // 2. qn = inorm(q1)
    hipLaunchKernelGGL(inorm_k, dim3(128), blk, 0, stream, tmp, qn);
    // 3. ref points + softmax sample weights
    hipLaunchKernelGGL(offsw_k, dim3(HW), dim3(64), 0, stream,
                       qn, bev_pos, off_w, off_b, sw_w, sw_b, refp, swts);
    // 4. transpose feature levels to channel-last
    hipLaunchKernelGGL(transpose_feat_k, dim3((6 * 132 * 32 * 88 + 255) / 256), blk, 0, stream,
                       feat0, fT0, 32, 88);
    hipLaunchKernelGGL(transpose_feat_k, dim3((6 * 132 * 16 * 44 + 255) / 256), blk, 0, stream,
                       feat1, fT1, 16, 44);
    hipLaunchKernelGGL(transpose_feat_k, dim3((6 * 132 * 8 * 22 + 255) / 256), blk, 0, stream,
                       feat2, fT2, 8, 22);
    hipLaunchKernelGGL(transpose_feat_k, dim3((6 * 132 * 4 * 11 + 255) / 256), blk, 0, stream,
                       feat3, fT3, 4, 11);
    // 5. deformable sampling + distance-weighted fold -> sf[256][pix]
    hipLaunchKernelGGL(sample_k, dim3(HW), dim3(128), 0, stream,
                       refp, swts, l2i, fT0, fT1, fT2, fT3, sf);
    // 6. m1 = gelu(conv3x3(sf, 256->512))
    hipLaunchKernelGGL((conv_k<256, 3, true, false>), dim3(PX, 512), blk,
                       256 * 9 * sizeof(float), stream,
                       sf, mid_w1, mid_b1, nullptr, m1);
    // 7. m2 = gelu(conv1x1(m1, 512->512))
    hipLaunchKernelGGL((conv1x1_k<512, true>), dim3(PX, 512), blk,
                       512 * sizeof(float), stream,
                       m1, mid_w2, mid_b2, m2);
    // 8. q2 = qn + conv3x3(m2, 512->128)
    hipLaunchKernelGGL((conv_k<512, 3, false, true>), dim3(PX, 128), blk,
                       512 * 9 * sizeof(float), stream,
                       m2, mid_w3, mid_b3, qn, tmp);
    // 9. q2n = inorm(q2)  (reuse qn buffer)
    hipLaunchKernelGGL(inorm_k, dim3(128), blk, 0, stream, tmp, qn);
    // 10. q3 = q2n + conv5x5(q2n, 128->128)
    hipLaunchKernelGGL((conv_k<128, 5, false, true>), dim3(PX, 128), blk,
                       128 * 25 * sizeof(float), stream,
                       qn, out_w, out_b, qn, tmp);
    // 11. out = inorm(q3)
    hipLaunchKernelGGL(inorm_k, dim3(128), blk, 0, stream, tmp, out);
}

// Round 3
// 998.256 us; speedup vs baseline: 7.3836x; 7.3836x over previous
//
#include <hip/hip_runtime.h>
#include <cstddef>

// ---------------------------------------------------------------------------
// SegTransformerDecoder — round 3.
// Decision chain (conv1 -> inorm -> offs/sw) in exact fp32 (valid-flag flips
// killed round 2); post-sampling convs in bf16 MFMA implicit GEMM with
// slab-store K-split (no atomics).
// ---------------------------------------------------------------------------

#define HW   10000
#define WID  100

typedef __attribute__((ext_vector_type(8))) __bf16 bf16x8;
typedef __attribute__((ext_vector_type(4))) float f32x4;
typedef __attribute__((ext_vector_type(4))) unsigned int uint4v;

__device__ __forceinline__ float gelu_exact(float x) {
    return 0.5f * x * (1.0f + erff(x * 0.7071067811865475f));
}
__device__ __forceinline__ unsigned short f2bf(float v) {
    unsigned int b = __float_as_uint(v);
    return (unsigned short)((b + 0x7FFFu + ((b >> 16) & 1u)) >> 16);
}
__device__ __forceinline__ bf16x8 load_frag(const short* p) {
    return __builtin_bit_cast(bf16x8, *(const uint4v*)p);
}

// ---------------------------------------------------------------------------
// fp32 implicit-GEMM conv 5x5, CIN=COUT=128, input channel-last padded(2) fp32
// weights packed [ky][kx][ic][oc] fp32.  Block tile 128oc x 64pix (2 rows x 32),
// thread = 8oc x 4pix.  K-split over ky (3 slabs), slab[z][oc][pix] plain store.
// grid (4, 50, 3), block 256.
// ---------------------------------------------------------------------------
__global__ __launch_bounds__(256)
void conv1_f32(const float* __restrict__ wpkf, const float* __restrict__ xpad,
               float* __restrict__ slab)
{
    __shared__ float As[16 * 128];
    __shared__ float Bs[16 * 68];
    const int t  = threadIdx.x;
    const int og = t >> 4, pg = t & 15;
    const int x0 = blockIdx.x * 32, y0 = blockIdx.y * 2;
    const int z  = blockIdx.z;
    const int ky_lo = z * 2;
    const int ky_hi = (ky_lo + 2 < 5) ? ky_lo + 2 : 5;

    const int cpix = t >> 2;              // 0..63
    const int cpy = cpix >> 5, cpx = cpix & 31;
    const int cj  = (t & 3) * 4;          // 0,4,8,12

    float acc[8][4];
#pragma unroll
    for (int i = 0; i < 8; ++i)
#pragma unroll
        for (int j = 0; j < 4; ++j) acc[i][j] = 0.f;

    for (int ky = ky_lo; ky < ky_hi; ++ky) {
        for (int kx = 0; kx < 5; ++kx) {
            for (int ic0 = 0; ic0 < 128; ic0 += 16) {
                __syncthreads();
                const float* asrc = wpkf + (size_t)((ky * 5 + kx) * 128 + ic0) * 128;
                *(float4*)(As + t * 8)     = *(const float4*)(asrc + t * 8);
                *(float4*)(As + t * 8 + 4) = *(const float4*)(asrc + t * 8 + 4);
                const float* bsrc = xpad +
                    (size_t)((y0 + cpy + ky) * 104 + x0 + cpx + kx) * 128 + ic0 + cj;
                const float4 bv = *(const float4*)bsrc;
                Bs[(cj + 0) * 68 + cpix] = bv.x;
                Bs[(cj + 1) * 68 + cpix] = bv.y;
                Bs[(cj + 2) * 68 + cpix] = bv.z;
                Bs[(cj + 3) * 68 + cpix] = bv.w;
                __syncthreads();
#pragma unroll
                for (int k = 0; k < 16; ++k) {
                    float a[8], b[4];
                    *(float4*)a       = *(float4*)(As + k * 128 + og * 8);
                    *(float4*)(a + 4) = *(float4*)(As + k * 128 + og * 8 + 4);
                    *(float4*)b       = *(float4*)(Bs + k * 68 + pg * 4);
#pragma unroll
                    for (int i = 0; i < 8; ++i)
#pragma unroll
                        for (int j = 0; j < 4; ++j)
                            acc[i][j] = fmaf(a[i], b[j], acc[i][j]);
                }
            }
        }
    }

    float* sl = slab + (size_t)z * 1280000;
#pragma unroll
    for (int j = 0; j < 4; ++j) {
        const int p  = pg * 4 + j;
        const int gx = x0 + (p & 31);
        const int gy = y0 + (p >> 5);
        if (gx >= 100) continue;
        const int pix = gy * WID + gx;
#pragma unroll
        for (int i = 0; i < 8; ++i)
            sl[(size_t)(og * 8 + i) * HW + pix] = acc[i][j];
    }
}

// ---------------------------------------------------------------------------
// bf16 MFMA implicit-GEMM conv. block 256 (4 waves 2x2), tile 64oc x 128pix.
// grid (COUT/64, 25, 4*KSPLIT).
// EPI==1: bf16 channel-last padded out (+bias, opt GELU)
// EPI==2: fp32 slab[ks][oc][pix] plain store (reduce adds bias+res later)
// ---------------------------------------------------------------------------
template<int CIN, int KS, int COUT, int EPI, bool ACT, int OPAD, int OPW, int KSPLIT>
__global__ __launch_bounds__(256)
void mfma_conv(const short* __restrict__ wpk, const short* __restrict__ xcl,
               const float* __restrict__ bias,
               float* __restrict__ outcm, short* __restrict__ outcl)
{
    constexpr int PW = 100 + 2 * (KS / 2);
    constexpr int CHUNK = (KS + KSPLIT - 1) / KSPLIT;
    const int lane = threadIdx.x & 63;
    const int wave = threadIdx.x >> 6;
    const int wm = (wave >> 1) * 32;
    const int wn = (wave & 1) * 64;
    const int lq = lane >> 4;
    const int ln = lane & 15;

    const int oc0 = blockIdx.x * 64;
    const int y0  = blockIdx.y * 4;
    const int zb  = blockIdx.z;
    const int bx  = (KSPLIT > 1) ? (zb & 3) : zb;
    const int ks  = (KSPLIT > 1) ? (zb >> 2) : 0;
    const int x0  = bx * 32;
    const int ky_lo = ks * CHUNK;
    const int ky_hi = (ky_lo + CHUNK < KS) ? ky_lo + CHUNK : KS;

    int bpix[4];
#pragma unroll
    for (int nt = 0; nt < 4; ++nt) {
        const int nl = wn + nt * 16 + ln;
        bpix[nt] = (y0 + (nl >> 5)) * PW + (x0 + (nl & 31));
    }

    f32x4 acc[2][4];
#pragma unroll
    for (int mt = 0; mt < 2; ++mt)
#pragma unroll
        for (int nt = 0; nt < 4; ++nt)
#pragma unroll
            for (int r = 0; r < 4; ++r) acc[mt][nt][r] = 0.f;

    const int arow0 = oc0 + wm + ln;

    for (int ky = ky_lo; ky < ky_hi; ++ky) {
#pragma unroll
        for (int kx = 0; kx < KS; ++kx) {
            const short* wsl = wpk + (size_t)((ky * KS + kx) * COUT) * CIN;
            const short* xsl = xcl + (size_t)(ky * PW + kx) * CIN;
            for (int ic0 = 0; ic0 < CIN; ic0 += 32) {
                bf16x8 a[2], b[4];
#pragma unroll
                for (int mt = 0; mt < 2; ++mt)
                    a[mt] = load_frag(wsl + (size_t)(arow0 + mt * 16) * CIN + ic0 + lq * 8);
#pragma unroll
                for (int nt = 0; nt < 4; ++nt)
                    b[nt] = load_frag(xsl + (size_t)bpix[nt] * CIN + ic0 + lq * 8);
#pragma unroll
                for (int mt = 0; mt < 2; ++mt)
#pragma unroll
                    for (int nt = 0; nt < 4; ++nt)
                        acc[mt][nt] = __builtin_amdgcn_mfma_f32_16x16x32_bf16(
                            a[mt], b[nt], acc[mt][nt], 0, 0, 0);
            }
        }
    }

#pragma unroll
    for (int mt = 0; mt < 2; ++mt) {
        const int ocr = oc0 + wm + mt * 16 + lq * 4;
        float bb[4];
        if (EPI == 1) {
            const float4 bv = *(const float4*)(bias + ocr);
            bb[0] = bv.x; bb[1] = bv.y; bb[2] = bv.z; bb[3] = bv.w;
        }
#pragma unroll
        for (int nt = 0; nt < 4; ++nt) {
            const int nl = wn + nt * 16 + ln;
            const int x = x0 + (nl & 31);
            const int y = y0 + (nl >> 5);
            if (x >= 100) continue;
            if (EPI == 1) {
                float v[4];
#pragma unroll
                for (int r = 0; r < 4; ++r) {
                    float t = acc[mt][nt][r] + bb[r];
                    if (ACT) t = gelu_exact(t);
                    v[r] = t;
                }
                ushort4 pk;
                pk.x = f2bf(v[0]); pk.y = f2bf(v[1]); pk.z = f2bf(v[2]); pk.w = f2bf(v[3]);
                *(ushort4*)(outcl + ((size_t)(y + OPAD) * OPW + (x + OPAD)) * COUT + ocr) = pk;
            } else {
                const int pix = y * WID + x;
#pragma unroll
                for (int r = 0; r < 4; ++r)
                    outcm[((size_t)ks * COUT + ocr + r) * HW + pix] = acc[mt][nt][r];
            }
        }
    }
}

// out = bias + res + slab0 + slab1 + slab2   (128 x HW)
__global__ void reduce3_k(const float* __restrict__ bias, const float* __restrict__ res,
                          const float* __restrict__ slab, float* __restrict__ out)
{
    const int i = blockIdx.x * blockDim.x + threadIdx.x;
    if (i >= 128 * HW) return;
    const int c = i / HW;
    out[i] = bias[c] + res[i] + slab[i] + slab[1280000 + i] + slab[2560000 + i];
}

// fp32 channel-major [128][100][100] -> fp32 channel-last padded(2) [104][104][128]
__global__ void pad_cl_f32(const float* __restrict__ in, float* __restrict__ out)
{
    const int total = 104 * 104 * 128;
    for (int i = blockIdx.x * blockDim.x + threadIdx.x; i < total; i += gridDim.x * blockDim.x) {
        const int c = i % 128;
        const int p = i / 128;
        const int x = p % 104 - 2;
        const int y = p / 104 - 2;
        float v = 0.f;
        if (x >= 0 && x < 100 && y >= 0 && y < 100) v = in[(size_t)c * HW + y * WID + x];
        out[i] = v;
    }
}

// fp32 channel-major -> bf16 channel-last padded
template<int C, int PAD>
__global__ void pad_cl_cast(const float* __restrict__ in, short* __restrict__ out)
{
    constexpr int PW = 100 + 2 * PAD;
    const int total = PW * PW * C;
    for (int i = blockIdx.x * blockDim.x + threadIdx.x; i < total; i += gridDim.x * blockDim.x) {
        const int c = i % C;
        const int p = i / C;
        const int x = p % PW - PAD;
        const int y = p / PW - PAD;
        float v = 0.f;
        if (x >= 0 && x < 100 && y >= 0 && y < 100) v = in[(size_t)c * HW + y * WID + x];
        out[i] = (short)f2bf(v);
    }
}

// fp32 [oc][ic][ky][kx] -> bf16 [ky][kx][oc][ic]
template<int OC, int CI, int KS>
__global__ void pack_w(const float* __restrict__ w, short* __restrict__ out)
{
    const int total = OC * CI * KS * KS;
    for (int i = blockIdx.x * blockDim.x + threadIdx.x; i < total; i += gridDim.x * blockDim.x) {
        const int ic = i % CI;
        int t = i / CI;
        const int oc = t % OC;
        const int s = t / OC;
        const int ky = s / KS, kx = s % KS;
        out[i] = (short)f2bf(w[(((size_t)oc * CI + ic) * KS + ky) * KS + kx]);
    }
}

// fp32 [oc][ic][5][5] -> fp32 [ky][kx][ic][oc]  (conv1)
__global__ void pack_w1_f32(const float* __restrict__ w, float* __restrict__ out)
{
    const int total = 128 * 128 * 25;
    for (int i = blockIdx.x * blockDim.x + threadIdx.x; i < total; i += gridDim.x * blockDim.x) {
        const int oc = i % 128;
        int t = i / 128;
        const int ic = t % 128;
        const int s = t / 128;
        const int ky = s / 5, kx = s % 5;
        out[i] = w[(((size_t)oc * 128 + ic) * 5 + ky) * 5 + kx];
    }
}

// Instance norm; one block (256 thr) per channel.
__global__ void inorm_k(const float* __restrict__ in, float* __restrict__ out)
{
    const int c = blockIdx.x;
    const float* p = in + (size_t)c * HW;
    __shared__ float red[256];
    const int tid = threadIdx.x;

    float s = 0.f;
    for (int i = tid; i < HW; i += 256) s += p[i];
    red[tid] = s; __syncthreads();
    for (int o = 128; o > 0; o >>= 1) { if (tid < o) red[tid] += red[tid + o]; __syncthreads(); }
    const float mean = red[0] * 1e-4f;
    __syncthreads();

    float v = 0.f;
    for (int i = tid; i < HW; i += 256) { const float d = p[i] - mean; v += d * d; }
    red[tid] = v; __syncthreads();
    for (int o = 128; o > 0; o >>= 1) { if (tid < o) red[tid] += red[tid + o]; __syncthreads(); }
    const float rstd = rsqrtf(red[0] * 1e-4f + 1e-5f);

    float* op = out + (size_t)c * HW;
    for (int i = tid; i < HW; i += 256) op[i] = (p[i] - mean) * rstd;
}

// Fused offsets/weights head (fp32). grid = HW blocks of 64 threads.
__global__ void offsw_k(const float* __restrict__ qn, const float* __restrict__ bev_pos,
                        const float* __restrict__ off_w, const float* __restrict__ off_b,
                        const float* __restrict__ sw_w, const float* __restrict__ sw_b,
                        float* __restrict__ refp, float* __restrict__ swts)
{
    const int pix = blockIdx.x;
    const int tid = threadIdx.x;
    __shared__ float qv[128];
    __shared__ float swraw[32];
    qv[tid]      = qn[(size_t)tid * HW + pix];
    qv[tid + 64] = qn[(size_t)(tid + 64) * HW + pix];
    __syncthreads();

    if (tid < 24) {
        float acc = off_b[tid];
        for (int c = 0; c < 128; ++c) acc = fmaf(qv[c], off_w[tid * 128 + c], acc);
        const float s = 1.0f / (1.0f + expf(-acc));
        const int coord = tid % 3;
        const float rng = (coord < 2) ? 0.250001f : 4.000001f;
        const float v = s * rng * 2.0f - rng;
        const float lo[3]   = {-50.f, -50.f, -5.f};
        const float span[3] = {100.f, 100.f, 8.f};
        refp[pix * 24 + tid] = bev_pos[pix * 3 + coord] * span[coord] + lo[coord] + v;
    } else if (tid >= 32) {
        const int j = tid - 32;
        float acc = sw_b[j];
        for (int c = 0; c < 128; ++c) acc = fmaf(qv[c], sw_w[j * 128 + c], acc);
        swraw[j] = acc;
    }
    __syncthreads();
    if (tid < 8) {
        float m = -1e30f;
#pragma unroll
        for (int l = 0; l < 4; ++l) m = fmaxf(m, swraw[tid * 4 + l]);
        float e[4], sum = 0.f;
#pragma unroll
        for (int l = 0; l < 4; ++l) { e[l] = expf(swraw[tid * 4 + l] - m); sum += e[l]; }
        const float inv = 1.0f / sum;
#pragma unroll
        for (int l = 0; l < 4; ++l) swts[pix * 32 + tid * 4 + l] = e[l] * inv;
    }
}

// [n][c][y][x] (c=132) -> [n][y][x][c]  fp32
__global__ void transpose_feat_k(const float* __restrict__ in, float* __restrict__ out,
                                 int Hl, int Wl)
{
    const int total = 6 * 132 * Hl * Wl;
    for (int i = blockIdx.x * blockDim.x + threadIdx.x; i < total; i += gridDim.x * blockDim.x) {
        int c = i % 132;
        int t = i / 132;
        const int x = t % Wl; t /= Wl;
        const int y = t % Hl; t /= Hl;
        const int n = t;
        out[i] = in[(((size_t)n * 132 + c) * Hl + y) * Wl + x];
    }
}

// Deformable sampling + distance-weighted fold -> sf bf16 channel-last padded(1)
__global__ void sample_k(const float* __restrict__ refp, const float* __restrict__ swts,
                         const float* __restrict__ l2i,
                         const float* __restrict__ fT0, const float* __restrict__ fT1,
                         const float* __restrict__ fT2, const float* __restrict__ fT3,
                         short* __restrict__ sfo)
{
    const int pix = blockIdx.x;
    const int tid = threadIdx.x;
    __shared__ float rp[24], sw[32], M[96], tailv[32];
    if (tid < 24) rp[tid] = refp[pix * 24 + tid];
    if (tid < 32) sw[tid] = swts[pix * 32 + tid];
    if (tid < 96) M[tid]  = l2i[tid];
    __syncthreads();

    const float* fT[4] = {fT0, fT1, fT2, fT3};
    const int HL[4] = {32, 16, 8, 4};
    const int WL[4] = {88, 44, 22, 11};

    float sf1 = 0.f, sf2 = 0.f;
    for (int p = 0; p < 8; ++p) {
        float acc = 0.f, accT = 0.f;
        const float X = rp[p * 3], Y = rp[p * 3 + 1], Z = rp[p * 3 + 2];
        for (int n = 0; n < 6; ++n) {
            const float* m = M + n * 16;
            const float cx = m[0] * X + m[1] * Y + m[2]  * Z + m[3];
            const float cy = m[4] * X + m[5] * Y + m[6]  * Z + m[7];
            const float cz = m[8] * X + m[9] * Y + m[10] * Z + m[11];
            const bool valid = cz > 1e-5f;
            const float zz = fmaxf(cz, 1e-5f);
            const float gx = valid ? (cx / zz) * (2.0f / 704.0f) - 1.0f : -2.0f;
            const float gy = valid ? (cy / zz) * (2.0f / 256.0f) - 1.0f : -2.0f;
#pragma unroll
            for (int l = 0; l < 4; ++l) {
                const float wl = sw[p * 4 + l];
                const int Hl = HL[l], Wl = WL[l];
                const float fx = (gx + 1.0f) * 0.5f * (float)Wl - 0.5f;
                const float fy = (gy + 1.0f) * 0.5f * (float)Hl - 0.5f;
                if (!(fx >= -1.0f && fx < (float)Wl && fy >= -1.0f && fy < (float)Hl))
                    continue;
                const float x0f = floorf(fx), y0f = floorf(fy);
                const int x0 = (int)x0f, y0 = (int)y0f;
                const int x1 = x0 + 1, y1 = y0 + 1;
                const float wx1 = fx - x0f, wy1 = fy - y0f;
                const float wx0 = 1.0f - wx1, wy0 = 1.0f - wy1;
                const bool okx0 = (x0 >= 0), okx1 = (x1 < Wl);
                const bool oky0 = (y0 >= 0), oky1 = (y1 < Hl);
                const float* fb = fT[l] + (size_t)n * Hl * Wl * 132;
                if (okx0 && oky0) {
                    const float wt = wx0 * wy0 * wl;
                    const float* tp = fb + (size_t)(y0 * Wl + x0) * 132;
                    acc = fmaf(tp[tid], wt, acc);
                    if (tid < 4) accT = fmaf(tp[128 + tid], wt, accT);
                }
                if (okx1 && oky0) {
                    const float wt = wx1 * wy0 * wl;
                    const float* tp = fb + (size_t)(y0 * Wl + x1) * 132;
                    acc = fmaf(tp[tid], wt, acc);
                    if (tid < 4) accT = fmaf(tp[128 + tid], wt, accT);
                }
                if (okx0 && oky1) {
                    const float wt = wx0 * wy1 * wl;
                    const float* tp = fb + (size_t)(y1 * Wl + x0) * 132;
                    acc = fmaf(tp[tid], wt, acc);
                    if (tid < 4) accT = fmaf(tp[128 + tid], wt, accT);
                }
                if (okx1 && oky1) {
                    const float wt = wx1 * wy1 * wl;
                    const float* tp = fb + (size_t)(y1 * Wl + x1) * 132;
                    acc = fmaf(tp[tid], wt, acc);
                    if (tid < 4) accT = fmaf(tp[128 + tid], wt, accT);
                }
            }
        }
        if (tid < 4) tailv[p * 4 + tid] = accT;
        __syncthreads();
        const float dx = X - tailv[p * 4 + 0];
        const float dy = Y - tailv[p * 4 + 1];
        const float dz = Z - tailv[p * 4 + 2];
        const float wgt = expf(-0.1f * (dx * dx + dy * dy + dz * dz));
        sf1 += acc;
        sf2 += acc * wgt;
        __syncthreads();
    }
    const int y = pix / WID, x = pix % WID;
    const size_t po = ((size_t)(y + 1) * 102 + (x + 1)) * 256;
    sfo[po + tid]       = (short)f2bf(sf1);
    sfo[po + 128 + tid] = (short)f2bf(sf2);
}

// ---------------------------------------------------------------------------

extern "C" void kernel_launch(void* const* d_in, const int* in_sizes, int n_in,
                              void* d_out, int out_size, void* d_ws, size_t ws_size,
                              hipStream_t stream)
{
    const float* bev_query = (const float*)d_in[0];
    const float* bev_pos   = (const float*)d_in[1];
    const float* l2i       = (const float*)d_in[2];
    const float* feat0     = (const float*)d_in[3];
    const float* feat1     = (const float*)d_in[4];
    const float* feat2     = (const float*)d_in[5];
    const float* feat3     = (const float*)d_in[6];
    const float* in_w      = (const float*)d_in[7];
    const float* in_b      = (const float*)d_in[8];
    const float* off_w     = (const float*)d_in[9];
    const float* off_b     = (const float*)d_in[10];
    const float* sw_w      = (const float*)d_in[11];
    const float* sw_b      = (const float*)d_in[12];
    const float* mid_w1    = (const float*)d_in[13];
    const float* mid_b1    = (const float*)d_in[14];
    const float* mid_w2    = (const float*)d_in[15];
    const float* mid_b2    = (const float*)d_in[16];
    const float* mid_w3    = (const float*)d_in[17];
    const float* mid_b3    = (const float*)d_in[18];
    const float* out_w     = (const float*)d_in[19];
    const float* out_b     = (const float*)d_in[20];
    float* out = (float*)d_out;

    // ---- workspace layout (aliased; ~55 MB total) ----
    float* ws    = (float*)d_ws;
    float* qn    = ws;                        // 1,280,000 f
    float* tmp   = qn + 1280000;              // 1,280,000 f
    float* refp  = tmp + 1280000;             //   240,000 f
    float* swts  = refp + 240000;             //   320,000 f
    float* slab  = swts + 320000;             // 3,840,000 f  (3 K-split slabs; fT alias)
    float* wpk1f = slab + 3840000;            //   409,600 f
    short* m1U   = (short*)(wpk1f + 409600);  // 5,130,000 sh (m1_cl | xpad_f32 | q2pad)
    short* m2U   = m1U + 5130000;             // 5,345,000 sh (m2_cl | sf_cl)
    short* wp_m1 = m2U + 5345000;             // 1,179,648 sh
    short* wp_m2 = wp_m1 + 1179648;           //   262,144 sh
    short* wp_m3 = wp_m2 + 262144;            //   589,824 sh
    short* wp_out= wp_m3 + 589824;            //   409,600 sh

    float* fT0 = slab;                        // fT alias inside slab (2,962,080 f)
    float* fT1 = fT0 + 6 * 132 * 32 * 88;
    float* fT2 = fT1 + 6 * 132 * 16 * 44;
    float* fT3 = fT2 + 6 * 132 * 8  * 22;
    float* xpadf = (float*)m1U;               // 1,388,000 f fits in m1U
    short* m1_cl = m1U;
    short* q2pad = m1U;
    short* sf_cl = m2U;
    short* m2_cl = m2U;

    const dim3 blk(256);

    // ---- weight packing ----
    hipLaunchKernelGGL(pack_w1_f32, dim3(1600), blk, 0, stream, in_w, wpk1f);
    hipLaunchKernelGGL((pack_w<512, 256, 3>), dim3(4608), blk, 0, stream, mid_w1, wp_m1);
    hipLaunchKernelGGL((pack_w<512, 512, 1>), dim3(1024), blk, 0, stream, mid_w2, wp_m2);
    hipLaunchKernelGGL((pack_w<128, 512, 3>), dim3(2304), blk, 0, stream, mid_w3, wp_m3);
    hipLaunchKernelGGL((pack_w<128, 128, 5>), dim3(1600), blk, 0, stream, out_w, wp_out);

    // ---- 1. q1 = bev_query + conv5x5_f32(bev_query) ----
    hipLaunchKernelGGL(pad_cl_f32, dim3(5411), blk, 0, stream, bev_query, xpadf);
    hipLaunchKernelGGL(conv1_f32, dim3(4, 50, 3), blk, 0, stream, wpk1f, xpadf, slab);
    hipLaunchKernelGGL(reduce3_k, dim3(5000), blk, 0, stream, in_b, bev_query, slab, tmp);
    // ---- 2. qn = inorm(q1) ----
    hipLaunchKernelGGL(inorm_k, dim3(128), blk, 0, stream, tmp, qn);
    // ---- 3. ref points + softmax weights (fp32) ----
    hipLaunchKernelGGL(offsw_k, dim3(HW), dim3(64), 0, stream,
                       qn, bev_pos, off_w, off_b, sw_w, sw_b, refp, swts);
    // ---- 4. feature transposes (into slab region; conv1 slabs are dead) ----
    hipLaunchKernelGGL(transpose_feat_k, dim3(8713), blk, 0, stream, feat0, fT0, 32, 88);
    hipLaunchKernelGGL(transpose_feat_k, dim3(2179), blk, 0, stream, feat1, fT1, 16, 44);
    hipLaunchKernelGGL(transpose_feat_k, dim3(545),  blk, 0, stream, feat2, fT2, 8, 22);
    hipLaunchKernelGGL(transpose_feat_k, dim3(137),  blk, 0, stream, feat3, fT3, 4, 11);
    // ---- 5. sampling -> sf_cl bf16 padded(1) ----
    hipMemsetAsync(sf_cl, 0, (size_t)2663424 * 2, stream);
    hipLaunchKernelGGL(sample_k, dim3(HW), dim3(128), 0, stream,
                       refp, swts, l2i, fT0, fT1, fT2, fT3, sf_cl);
    // ---- 6. m1 = gelu(conv3x3 256->512) ----
    hipLaunchKernelGGL((mfma_conv<256, 3, 512, 1, true, 0, 100, 1>), dim3(8, 25, 4), blk, 0, stream,
                       wp_m1, sf_cl, mid_b1, nullptr, m1_cl);
    // ---- 7. m2 = gelu(conv1x1 512->512) -> m2_cl padded(1) ----
    hipMemsetAsync(m2U, 0, (size_t)5326848 * 2, stream);
    hipLaunchKernelGGL((mfma_conv<512, 1, 512, 1, true, 1, 102, 1>), dim3(8, 25, 4), blk, 0, stream,
                       wp_m2, m1_cl, mid_b2, nullptr, m2_cl);
    // ---- 8. q2 = qn + conv3x3 512->128  (K-split 3, slabs) ----
    hipLaunchKernelGGL((mfma_conv<512, 3, 128, 2, false, 0, 0, 3>), dim3(2, 25, 12), blk, 0, stream,
                       wp_m3, m2_cl, mid_b3, slab, nullptr);
    hipLaunchKernelGGL(reduce3_k, dim3(5000), blk, 0, stream, mid_b3, qn, slab, tmp);
    // ---- 9. q2n = inorm(q2) ----
    hipLaunchKernelGGL(inorm_k, dim3(128), blk, 0, stream, tmp, qn);
    // ---- 10. q3 = q2n + conv5x5 bf16 (K-split 3, slabs) ----
    hipLaunchKernelGGL((pad_cl_cast<128, 2>), dim3(5411), blk, 0, stream, qn, q2pad);
    hipLaunchKernelGGL((mfma_conv<128, 5, 128, 2, false, 0, 0, 3>), dim3(2, 25, 12), blk, 0, stream,
                       wp_out, q2pad, out_b, slab, nullptr);
    hipLaunchKernelGGL(reduce3_k, dim3(5000), blk, 0, stream, out_b, qn, slab, tmp);
    // ---- 11. out = inorm(q3) ----
    hipLaunchKernelGGL(inorm_k, dim3(128), blk, 0, stream, tmp, out);
}